// Round 3
// baseline (236.734 us; speedup 1.0000x reference)
//
#include <hip/hip_runtime.h>

#define D_CH   1024
#define L_SEQ  8192
#define NCH    32                       /* channels per block (k2, 1ch/thread) */
#define W_N    3.8349519697141029e-4f   /* 2*pi/16384 */
#define W128A  4.90873852123405e-2f     /* 2*pi/128 */

// ---------------- bf16 pack/unpack --------------------------------------
__device__ __forceinline__ float bf2f(unsigned v){
  union { float f; unsigned u; } x; x.u = v << 16;
  return x.f;
}
// single-instruction RNE pack of (r,i) -> bf16|bf16<<16 (no builtin on gfx950)
__device__ __forceinline__ unsigned packc(float r, float i){
  unsigned u;
  asm("v_cvt_pk_bf16_f32 %0, %1, %2" : "=v"(u) : "v"(r), "v"(i));
  return u;
}
__device__ __forceinline__ float2 upk(unsigned u){
  return make_float2(bf2f(u & 0xffffu), bf2f(u >> 16));
}
// two packed complexes (channels A,B) -> float4 (Are,Aim,Bre,Bim)
__device__ __forceinline__ float4 upk2(uint2 u){
  return make_float4(bf2f(u.x & 0xffffu), bf2f(u.x >> 16),
                     bf2f(u.y & 0xffffu), bf2f(u.y >> 16));
}
// complex multiply both halves of a float4 by (cs + i*sn)
__device__ __forceinline__ float4 cmul2(float4 a, float cs, float sn){
  return make_float4(a.x*cs - a.y*sn, a.x*sn + a.y*cs,
                     a.z*cs - a.w*sn, a.z*sn + a.w*cs);
}

__device__ __host__ constexpr int bitrev4(int j){
  return ((j&1)<<3)|((j&2)<<1)|((j&4)>>1)|((j&8)>>3);
}
__device__ __host__ constexpr int bitrev3(int j){
  return ((j&1)<<2)|(j&2)|((j&4)>>2);
}

// ---------------- float2 (1 channel) DFT kernels (k2) -------------------
template<int SGN>
__device__ __forceinline__ void dft16(float2* x){
  const float TC[8] = {1.f, 0.9238795325f, 0.7071067812f, 0.3826834324f,
                       0.f, -0.3826834324f, -0.7071067812f, -0.9238795325f};
  const float TS[8] = {0.f, -0.3826834324f, -0.7071067812f, -0.9238795325f,
                       -1.f, -0.9238795325f, -0.7071067812f, -0.3826834324f};
#pragma unroll
  for (int len = 16; len >= 2; len >>= 1){
    const int half = len >> 1, tstep = 16 / len;
#pragma unroll
    for (int st = 0; st < 16; st += len){
#pragma unroll
      for (int j = 0; j < half; j++){
        const float wr = TC[j*tstep];
        const float wi = (SGN > 0) ? TS[j*tstep] : -TS[j*tstep];
        const int a = st + j, b = a + half;
        const float ur = x[a].x, ui = x[a].y;
        const float vr = x[b].x, vi = x[b].y;
        x[a].x = ur + vr; x[a].y = ui + vi;
        const float dr = ur - vr, di = ui - vi;
        x[b].x = dr*wr - di*wi;
        x[b].y = dr*wi + di*wr;
      }
    }
  }
}

template<int SGN>
__device__ __forceinline__ void dft8(float2* x){
  const float TC[4] = {1.f, 0.7071067812f, 0.f, -0.7071067812f};
  const float TS[4] = {0.f, -0.7071067812f, -1.f, -0.7071067812f};
#pragma unroll
  for (int len = 8; len >= 2; len >>= 1){
    const int half = len >> 1, tstep = 8 / len;
#pragma unroll
    for (int st = 0; st < 8; st += len){
#pragma unroll
      for (int j = 0; j < half; j++){
        const float wr = TC[j*tstep];
        const float wi = (SGN > 0) ? TS[j*tstep] : -TS[j*tstep];
        const int a = st + j, b = a + half;
        const float ur = x[a].x, ui = x[a].y;
        const float vr = x[b].x, vi = x[b].y;
        x[a].x = ur + vr; x[a].y = ui + vi;
        const float dr = ur - vr, di = ui - vi;
        x[b].x = dr*wr - di*wi;
        x[b].y = dr*wi + di*wr;
      }
    }
  }
}

// ---------------- float4 (2 channels) DFT kernels (k1/k3) ---------------
template<int SGN>
__device__ __forceinline__ void dft16v4(float4* x){
  const float TC[8] = {1.f, 0.9238795325f, 0.7071067812f, 0.3826834324f,
                       0.f, -0.3826834324f, -0.7071067812f, -0.9238795325f};
  const float TS[8] = {0.f, -0.3826834324f, -0.7071067812f, -0.9238795325f,
                       -1.f, -0.9238795325f, -0.7071067812f, -0.3826834324f};
#pragma unroll
  for (int len = 16; len >= 2; len >>= 1){
    const int half = len >> 1, tstep = 16 / len;
#pragma unroll
    for (int st = 0; st < 16; st += len){
#pragma unroll
      for (int j = 0; j < half; j++){
        const float wr = TC[j*tstep];
        const float wi = (SGN > 0) ? TS[j*tstep] : -TS[j*tstep];
        const int a = st + j, b = a + half;
        const float4 u = x[a], v = x[b];
        x[a] = make_float4(u.x+v.x, u.y+v.y, u.z+v.z, u.w+v.w);
        const float4 dd = make_float4(u.x-v.x, u.y-v.y, u.z-v.z, u.w-v.w);
        x[b] = make_float4(dd.x*wr - dd.y*wi, dd.x*wi + dd.y*wr,
                           dd.z*wr - dd.w*wi, dd.z*wi + dd.w*wr);
      }
    }
  }
}

template<int SGN>
__device__ __forceinline__ void dft8v4(float4* x){
  const float TC[4] = {1.f, 0.7071067812f, 0.f, -0.7071067812f};
  const float TS[4] = {0.f, -0.7071067812f, -1.f, -0.7071067812f};
#pragma unroll
  for (int len = 8; len >= 2; len >>= 1){
    const int half = len >> 1, tstep = 8 / len;
#pragma unroll
    for (int st = 0; st < 8; st += len){
#pragma unroll
      for (int j = 0; j < half; j++){
        const float wr = TC[j*tstep];
        const float wi = (SGN > 0) ? TS[j*tstep] : -TS[j*tstep];
        const int a = st + j, b = a + half;
        const float4 u = x[a], v = x[b];
        x[a] = make_float4(u.x+v.x, u.y+v.y, u.z+v.z, u.w+v.w);
        const float4 dd = make_float4(u.x-v.x, u.y-v.y, u.z-v.z, u.w-v.w);
        x[b] = make_float4(dd.x*wr - dd.y*wi, dd.x*wi + dd.y*wr,
                           dd.z*wr - dd.w*wi, dd.z*wi + dd.w*wr);
      }
    }
  }
}

// Per-block twiddle table for fft128: twF[p*16+k] = e^{-i*2pi*p*k/128}.
__device__ __forceinline__ void build_twF(float2* twF, int tid){
  if (tid < 128){
    const int pp = tid >> 4, kk = tid & 15;
    float sn, cs;
    __sincosf(-W128A * (float)(pp * kk), &sn, &cs);
    twF[tid] = make_float2(cs, sn);
  }
}

// ---- 1-channel fft128 (k2): LDS float2[64*NCH] = 16 KiB ---------------
template<int SGN>
__device__ __forceinline__ void fft128(float2* v, float2* lds,
                                       const float2* twF, int ch, int p){
  dft16<SGN>(v);
#pragma unroll
  for (int slot = 0; slot < 8; slot++){
    const int r = bitrev3(slot);
    const float2 t = twF[p*16 + 2*r];
    const float cs = t.x;
    const float sn = (SGN > 0) ? t.y : -t.y;
    const float2 a = v[slot];
    lds[(p*8 + r)*NCH + ch] = make_float2(a.x*cs - a.y*sn, a.x*sn + a.y*cs);
  }
  __syncthreads();
  float2 t8[8];
#pragma unroll
  for (int pp = 0; pp < 8; pp++) t8[pp] = lds[(pp*8 + p)*NCH + ch]; // s=2p
  dft8<SGN>(t8);
#pragma unroll
  for (int t = 0; t < 8; t++) v[t] = t8[t];
  __syncthreads();
#pragma unroll
  for (int slot = 8; slot < 16; slot++){
    const int r = bitrev3(slot - 8);
    const float2 t = twF[p*16 + 2*r + 1];
    const float cs = t.x;
    const float sn = (SGN > 0) ? t.y : -t.y;
    const float2 a = v[slot];
    lds[(p*8 + r)*NCH + ch] = make_float2(a.x*cs - a.y*sn, a.x*sn + a.y*cs);
  }
  __syncthreads();
#pragma unroll
  for (int pp = 0; pp < 8; pp++) t8[pp] = lds[(pp*8 + p)*NCH + ch]; // s=2p+1
  dft8<SGN>(t8);
#pragma unroll
  for (int t = 0; t < 8; t++) v[8 + t] = t8[t];
}

// ---- 2-channel fft128 (k1/k3): LDS float4[64*32] = 32 KiB --------------
template<int SGN>
__device__ __forceinline__ void fft128v4(float4* v, float4* lds4,
                                         const float2* twF, int ch, int p){
  dft16v4<SGN>(v);
#pragma unroll
  for (int slot = 0; slot < 8; slot++){
    const int r = bitrev3(slot);
    const float2 t = twF[p*16 + 2*r];
    const float cs = t.x;
    const float sn = (SGN > 0) ? t.y : -t.y;
    lds4[(p*8 + r)*32 + ch] = cmul2(v[slot], cs, sn);
  }
  __syncthreads();
  float4 t8[8];
#pragma unroll
  for (int pp = 0; pp < 8; pp++) t8[pp] = lds4[(pp*8 + p)*32 + ch]; // s=2p
  dft8v4<SGN>(t8);
#pragma unroll
  for (int t = 0; t < 8; t++) v[t] = t8[t];
  __syncthreads();
#pragma unroll
  for (int slot = 8; slot < 16; slot++){
    const int r = bitrev3(slot - 8);
    const float2 t = twF[p*16 + 2*r + 1];
    const float cs = t.x;
    const float sn = (SGN > 0) ? t.y : -t.y;
    lds4[(p*8 + r)*32 + ch] = cmul2(v[slot], cs, sn);
  }
  __syncthreads();
#pragma unroll
  for (int pp = 0; pp < 8; pp++) t8[pp] = lds4[(pp*8 + p)*32 + ch]; // s=2p+1
  dft8v4<SGN>(t8);
#pragma unroll
  for (int t = 0; t < 8; t++) v[8 + t] = t8[t];
}

// ---------------------------------------------------------------------------
// K1: forward step1 over n1 (64 nonzero of 128, zero-padded). 2 ch/thread.
// A[k1,n2] = w16384^{k1 n2} * DFT128_{n1}(z[n2+128 n1]).
// mode 0: z = x[0] + i x[1]; mode 1: h.
// ---------------------------------------------------------------------------
__global__ __launch_bounds__(256, 4)
void k1_step1(const float* __restrict__ x, const float* __restrict__ h,
              unsigned* __restrict__ Az, unsigned* __restrict__ Ah){
  __shared__ float4 lds4[64*32];
  __shared__ float2 twF[128];
  __shared__ float2 twO[128];
  const int n2 = blockIdx.x, dg = blockIdx.y, mode = blockIdx.z;
  const int tid = threadIdx.x;
  const int ch = tid & 31, p = tid >> 5;
  const int d = dg*64 + 2*ch;                    // channel pair (d, d+1)

  build_twF(twF, tid);
  if (tid >= 128 && tid < 256){
    const int k1v = tid - 128;
    float sn, cs;
    __sincosf(-W_N * (float)(k1v * n2), &sn, &cs);   // e^{-i 2pi k1 n2 /16384}
    twO[k1v] = make_float2(cs, sn);
  }

  float4 v[16];
  if (mode == 0){
    const float* x0 = x;
    const float* x1 = x + (size_t)L_SEQ * D_CH;
#pragma unroll
    for (int q = 0; q < 8; q++){
      const size_t off = (size_t)(n2 + 128*(p + 8*q)) * D_CH + d;
      const float2 a = *(const float2*)(x0 + off);
      const float2 b = *(const float2*)(x1 + off);
      v[q] = make_float4(a.x, b.x, a.y, b.y);
    }
  } else {
#pragma unroll
    for (int q = 0; q < 8; q++){
      const size_t off = (size_t)(n2 + 128*(p + 8*q)) * D_CH + d;
      const float2 a = *(const float2*)(h + off);
      v[q] = make_float4(a.x, 0.f, a.y, 0.f);
    }
  }
#pragma unroll
  for (int q = 8; q < 16; q++) v[q] = make_float4(0.f, 0.f, 0.f, 0.f);

  __syncthreads();                       // twiddle tables visible
  fft128v4<1>(v, lds4, twF, ch, p);

  unsigned* __restrict__ A = mode ? Ah : Az;
#pragma unroll
  for (int c = 0; c < 2; c++){
#pragma unroll
    for (int t = 0; t < 8; t++){
      const int k1v = (2*p + c) + 16*bitrev3(t);
      const float2 w = twO[k1v];
      const float4 r = cmul2(v[c*8 + t], w.x, w.y);
      *(uint2*)&A[((size_t)k1v*128 + n2)*D_CH + d] =
        make_uint2(packc(r.x, r.y), packc(r.z, r.w));
    }
  }
}

// ---------------------------------------------------------------------------
// K2 (fused, 1 ch/thread — register-pressure-bound): forward step2 for h
// (in-register Hspec) + forward step2 for z + pointwise Z*H/16384 +
// inverse DFT over k2, in place on A_z.
// ---------------------------------------------------------------------------
__global__ __launch_bounds__(256, 4)
void k2_zh(unsigned* __restrict__ Az, const unsigned* __restrict__ Ah){
  __shared__ float2 lds[64*NCH];
  __shared__ float2 twF[128];
  const int k1 = blockIdx.x, dg = blockIdx.y;
  const int tid = threadIdx.x;
  const int ch = tid & (NCH-1), p = tid >> 5;
  const int d = dg*NCH + ch;
  const size_t base = (size_t)k1 * 128 * D_CH + d;

  build_twF(twF, tid);

  unsigned ha[16], za[16];
#pragma unroll
  for (int q = 0; q < 16; q++)
    ha[q] = Ah[base + (size_t)(p + 8*q) * D_CH];
#pragma unroll
  for (int q = 0; q < 16; q++)
    za[q] = Az[base + (size_t)(p + 8*q) * D_CH];

  __syncthreads();                       // twF visible

  float2 v[16];
#pragma unroll
  for (int q = 0; q < 16; q++) v[q] = upk(ha[q]);
  fft128<1>(v, lds, twF, ch, p);
  unsigned hs[16];
  const float sc = 1.0f / 16384.0f;
#pragma unroll
  for (int i = 0; i < 16; i++) hs[i] = packc(v[i].x * sc, v[i].y * sc);
  __syncthreads();

#pragma unroll
  for (int q = 0; q < 16; q++) v[q] = upk(za[q]);
  fft128<1>(v, lds, twF, ch, p);

#pragma unroll
  for (int i = 0; i < 16; i++){
    const float2 hv = upk(hs[i]);
    const float zr = v[i].x, zi = v[i].y;
    v[i] = make_float2(zr*hv.x - zi*hv.y, zr*hv.y + zi*hv.x);
  }

  __syncthreads();
  float2 w[8];
#pragma unroll
  for (int c = 0; c < 2; c++)
#pragma unroll
    for (int t = 0; t < 8; t += 2){
      const int k2 = (2*p + c) + 16*bitrev3(t);
      lds[k2*NCH + ch] = v[c*8 + t];
    }
  __syncthreads();
#pragma unroll
  for (int q = 0; q < 8; q++) w[q] = lds[(p + 8*q)*NCH + ch];
  __syncthreads();
#pragma unroll
  for (int c = 0; c < 2; c++)
#pragma unroll
    for (int t = 1; t < 8; t += 2){
      const int k2 = (2*p + c) + 16*bitrev3(t) - 64;
      lds[k2*NCH + ch] = v[c*8 + t];
    }
  __syncthreads();
#pragma unroll
  for (int q = 0; q < 8; q++) v[8 + q] = lds[(p + 8*q)*NCH + ch];
  __syncthreads();
#pragma unroll
  for (int q = 0; q < 8; q++) v[q] = w[q];

  fft128<-1>(v, lds, twF, ch, p);

#pragma unroll
  for (int c = 0; c < 2; c++){
#pragma unroll
    for (int t = 0; t < 8; t++){
      const int m2 = (2*p + c) + 16*bitrev3(t);
      const float2 a = v[c*8 + t];
      Az[base + (size_t)m2 * D_CH] = packc(a.x, a.y);
    }
  }
}

// ---------------------------------------------------------------------------
// K3: inverse step2 over k1 + bias + output write. 2 ch/thread.
// y[0,t,d] = Re(w)+bias, y[1,t,d] = Im(w)+bias, t = m2 + 128*m1, m1 < 64.
// ---------------------------------------------------------------------------
__global__ __launch_bounds__(256, 4)
void k3_inv2(const unsigned* __restrict__ Bz, const float* __restrict__ bias,
             float* __restrict__ out){
  __shared__ float4 lds4[64*32];
  __shared__ float2 twF[128];
  __shared__ float2 twI[128];
  const int m2 = blockIdx.x, dg = blockIdx.y;
  const int tid = threadIdx.x;
  const int ch = tid & 31, p = tid >> 5;
  const int d = dg*64 + 2*ch;
  const float2 bv = *(const float2*)(bias + d);

  build_twF(twF, tid);
  if (tid >= 128 && tid < 256){
    const int k1 = tid - 128;
    float sn, cs;
    __sincosf(W_N * (float)(m2 * k1), &sn, &cs);     // e^{+i 2pi m2 k1 /16384}
    twI[k1] = make_float2(cs, sn);
  }

  uint2 raw[16];
#pragma unroll
  for (int q = 0; q < 16; q++){
    const int k1 = p + 8*q;
    raw[q] = *(const uint2*)&Bz[((size_t)k1*128 + m2) * D_CH + d];
  }

  __syncthreads();                       // tables visible

  float4 v[16];
#pragma unroll
  for (int q = 0; q < 16; q++){
    const float2 w = twI[p + 8*q];
    v[q] = cmul2(upk2(raw[q]), w.x, w.y);
  }

  fft128v4<-1>(v, lds4, twF, ch, p);     // v[c*8+t] at m1=(2p+c)+16*bitrev3(t)

#pragma unroll
  for (int c = 0; c < 2; c++){
#pragma unroll
    for (int t = 0; t < 8; t += 2){      // t even <=> m1 < 64
      const int m1 = (2*p + c) + 16*bitrev3(t);
      const int tseq = m2 + 128*m1;
      const float4 a = v[c*8 + t];
      *(float2*)&out[(size_t)tseq * D_CH + d] =
        make_float2(a.x + bv.x, a.z + bv.y);
      *(float2*)&out[(size_t)(L_SEQ + tseq) * D_CH + d] =
        make_float2(a.y + bv.x, a.w + bv.y);
    }
  }
}

// ---------------------------------------------------------------------------
extern "C" void kernel_launch(void* const* d_in, const int* in_sizes, int n_in,
                              void* d_out, int out_size, void* d_ws, size_t ws_size,
                              hipStream_t stream){
  (void)in_sizes; (void)n_in; (void)out_size;
  const float* x    = (const float*)d_in[0];
  const float* h    = (const float*)d_in[1];
  const float* bias = (const float*)d_in[2];
  float* out = (float*)d_out;

  const size_t REGION = (size_t)128 * 128 * D_CH * sizeof(unsigned); // 64 MiB
  unsigned *r1, *r2;
  if (ws_size >= 2 * REGION){
    r1 = (unsigned*)d_ws;                       // A_z -> b
    r2 = (unsigned*)((char*)d_ws + REGION);     // A_h
  } else {
    r1 = (unsigned*)d_out;  // safe: K3 reads each r1 cell before its stores
    r2 = (unsigned*)d_ws;   // requires ws_size >= 64 MiB
  }

  const dim3 blk(256, 1, 1);
  hipLaunchKernelGGL(k1_step1, dim3(128,16,2), blk, 0, stream, x, h, r1, r2);
  hipLaunchKernelGGL(k2_zh,    dim3(128,32,1), blk, 0, stream, r1, r2);
  hipLaunchKernelGGL(k3_inv2,  dim3(128,16,1), blk, 0, stream, r1, bias, out);
}

// Round 4
// 236.432 us; speedup vs baseline: 1.0013x; 1.0013x over previous
//
#include <hip/hip_runtime.h>

#define D_CH   1024
#define L_SEQ  8192
#define NCH    32                       /* channels per block (k2, 1ch/thread) */
#define W_N    3.8349519697141029e-4f   /* 2*pi/16384 */
#define W128A  4.90873852123405e-2f     /* 2*pi/128 */

// ---------------- bf16 pack/unpack --------------------------------------
__device__ __forceinline__ float bf2f(unsigned v){
  union { float f; unsigned u; } x; x.u = v << 16;
  return x.f;
}
// single-instruction RNE pack of (r,i) -> bf16|bf16<<16 (no builtin on gfx950)
__device__ __forceinline__ unsigned packc(float r, float i){
  unsigned u;
  asm("v_cvt_pk_bf16_f32 %0, %1, %2" : "=v"(u) : "v"(r), "v"(i));
  return u;
}
__device__ __forceinline__ float2 upk(unsigned u){
  return make_float2(bf2f(u & 0xffffu), bf2f(u >> 16));
}
// two packed complexes (channels A,B) -> float4 (Are,Aim,Bre,Bim)
__device__ __forceinline__ float4 upk2(unsigned ua, unsigned ub){
  return make_float4(bf2f(ua & 0xffffu), bf2f(ua >> 16),
                     bf2f(ub & 0xffffu), bf2f(ub >> 16));
}
// complex multiply both halves of a float4 by (cs + i*sn)
__device__ __forceinline__ float4 cmul2(float4 a, float cs, float sn){
  return make_float4(a.x*cs - a.y*sn, a.x*sn + a.y*cs,
                     a.z*cs - a.w*sn, a.z*sn + a.w*cs);
}

__device__ __host__ constexpr int bitrev4(int j){
  return ((j&1)<<3)|((j&2)<<1)|((j&4)>>1)|((j&8)>>3);
}
__device__ __host__ constexpr int bitrev3(int j){
  return ((j&1)<<2)|(j&2)|((j&4)>>2);
}

// ---------------- float2 (1 channel) DFT kernels (k2) -------------------
template<int SGN>
__device__ __forceinline__ void dft16(float2* x){
  const float TC[8] = {1.f, 0.9238795325f, 0.7071067812f, 0.3826834324f,
                       0.f, -0.3826834324f, -0.7071067812f, -0.9238795325f};
  const float TS[8] = {0.f, -0.3826834324f, -0.7071067812f, -0.9238795325f,
                       -1.f, -0.9238795325f, -0.7071067812f, -0.3826834324f};
#pragma unroll
  for (int len = 16; len >= 2; len >>= 1){
    const int half = len >> 1, tstep = 16 / len;
#pragma unroll
    for (int st = 0; st < 16; st += len){
#pragma unroll
      for (int j = 0; j < half; j++){
        const float wr = TC[j*tstep];
        const float wi = (SGN > 0) ? TS[j*tstep] : -TS[j*tstep];
        const int a = st + j, b = a + half;
        const float ur = x[a].x, ui = x[a].y;
        const float vr = x[b].x, vi = x[b].y;
        x[a].x = ur + vr; x[a].y = ui + vi;
        const float dr = ur - vr, di = ui - vi;
        x[b].x = dr*wr - di*wi;
        x[b].y = dr*wi + di*wr;
      }
    }
  }
}

template<int SGN>
__device__ __forceinline__ void dft8(float2* x){
  const float TC[4] = {1.f, 0.7071067812f, 0.f, -0.7071067812f};
  const float TS[4] = {0.f, -0.7071067812f, -1.f, -0.7071067812f};
#pragma unroll
  for (int len = 8; len >= 2; len >>= 1){
    const int half = len >> 1, tstep = 8 / len;
#pragma unroll
    for (int st = 0; st < 8; st += len){
#pragma unroll
      for (int j = 0; j < half; j++){
        const float wr = TC[j*tstep];
        const float wi = (SGN > 0) ? TS[j*tstep] : -TS[j*tstep];
        const int a = st + j, b = a + half;
        const float ur = x[a].x, ui = x[a].y;
        const float vr = x[b].x, vi = x[b].y;
        x[a].x = ur + vr; x[a].y = ui + vi;
        const float dr = ur - vr, di = ui - vi;
        x[b].x = dr*wr - di*wi;
        x[b].y = dr*wi + di*wr;
      }
    }
  }
}

// ---------------- float4 (2 channels) DFT kernels (k1/k3) ---------------
template<int SGN>
__device__ __forceinline__ void dft16v4(float4* x){
  const float TC[8] = {1.f, 0.9238795325f, 0.7071067812f, 0.3826834324f,
                       0.f, -0.3826834324f, -0.7071067812f, -0.9238795325f};
  const float TS[8] = {0.f, -0.3826834324f, -0.7071067812f, -0.9238795325f,
                       -1.f, -0.9238795325f, -0.7071067812f, -0.3826834324f};
#pragma unroll
  for (int len = 16; len >= 2; len >>= 1){
    const int half = len >> 1, tstep = 16 / len;
#pragma unroll
    for (int st = 0; st < 16; st += len){
#pragma unroll
      for (int j = 0; j < half; j++){
        const float wr = TC[j*tstep];
        const float wi = (SGN > 0) ? TS[j*tstep] : -TS[j*tstep];
        const int a = st + j, b = a + half;
        const float4 u = x[a], v = x[b];
        x[a] = make_float4(u.x+v.x, u.y+v.y, u.z+v.z, u.w+v.w);
        const float4 dd = make_float4(u.x-v.x, u.y-v.y, u.z-v.z, u.w-v.w);
        x[b] = make_float4(dd.x*wr - dd.y*wi, dd.x*wi + dd.y*wr,
                           dd.z*wr - dd.w*wi, dd.z*wi + dd.w*wr);
      }
    }
  }
}

template<int SGN>
__device__ __forceinline__ void dft8v4(float4* x){
  const float TC[4] = {1.f, 0.7071067812f, 0.f, -0.7071067812f};
  const float TS[4] = {0.f, -0.7071067812f, -1.f, -0.7071067812f};
#pragma unroll
  for (int len = 8; len >= 2; len >>= 1){
    const int half = len >> 1, tstep = 8 / len;
#pragma unroll
    for (int st = 0; st < 8; st += len){
#pragma unroll
      for (int j = 0; j < half; j++){
        const float wr = TC[j*tstep];
        const float wi = (SGN > 0) ? TS[j*tstep] : -TS[j*tstep];
        const int a = st + j, b = a + half;
        const float4 u = x[a], v = x[b];
        x[a] = make_float4(u.x+v.x, u.y+v.y, u.z+v.z, u.w+v.w);
        const float4 dd = make_float4(u.x-v.x, u.y-v.y, u.z-v.z, u.w-v.w);
        x[b] = make_float4(dd.x*wr - dd.y*wi, dd.x*wi + dd.y*wr,
                           dd.z*wr - dd.w*wi, dd.z*wi + dd.w*wr);
      }
    }
  }
}

// Per-block twiddle table for fft128: twF[p*16+k] = e^{-i*2pi*p*k/128}.
__device__ __forceinline__ void build_twF(float2* twF, int tid){
  if (tid < 128){
    const int pp = tid >> 4, kk = tid & 15;
    float sn, cs;
    __sincosf(-W128A * (float)(pp * kk), &sn, &cs);
    twF[tid] = make_float2(cs, sn);
  }
}

// ---- 1-channel fft128 (k2): LDS float2[64*NCH] = 16 KiB ---------------
template<int SGN>
__device__ __forceinline__ void fft128(float2* v, float2* lds,
                                       const float2* twF, int ch, int p){
  dft16<SGN>(v);
#pragma unroll
  for (int slot = 0; slot < 8; slot++){
    const int r = bitrev3(slot);
    const float2 t = twF[p*16 + 2*r];
    const float cs = t.x;
    const float sn = (SGN > 0) ? t.y : -t.y;
    const float2 a = v[slot];
    lds[(p*8 + r)*NCH + ch] = make_float2(a.x*cs - a.y*sn, a.x*sn + a.y*cs);
  }
  __syncthreads();
  float2 t8[8];
#pragma unroll
  for (int pp = 0; pp < 8; pp++) t8[pp] = lds[(pp*8 + p)*NCH + ch]; // s=2p
  dft8<SGN>(t8);
#pragma unroll
  for (int t = 0; t < 8; t++) v[t] = t8[t];
  __syncthreads();
#pragma unroll
  for (int slot = 8; slot < 16; slot++){
    const int r = bitrev3(slot - 8);
    const float2 t = twF[p*16 + 2*r + 1];
    const float cs = t.x;
    const float sn = (SGN > 0) ? t.y : -t.y;
    const float2 a = v[slot];
    lds[(p*8 + r)*NCH + ch] = make_float2(a.x*cs - a.y*sn, a.x*sn + a.y*cs);
  }
  __syncthreads();
#pragma unroll
  for (int pp = 0; pp < 8; pp++) t8[pp] = lds[(pp*8 + p)*NCH + ch]; // s=2p+1
  dft8<SGN>(t8);
#pragma unroll
  for (int t = 0; t < 8; t++) v[8 + t] = t8[t];
}

// ---- 4-channel fft128 (k1/k3): two float4 pairs, dual 32-KiB LDS -------
// Same cooperative structure, both channel-pairs advance per phase so the
// barrier count stays 3.
template<int SGN>
__device__ __forceinline__ void fft128v4x2(float4* vA, float4* vB,
                                           float4* ldsA, float4* ldsB,
                                           const float2* twF, int ch, int p){
  dft16v4<SGN>(vA);
  dft16v4<SGN>(vB);
#pragma unroll
  for (int slot = 0; slot < 8; slot++){
    const int r = bitrev3(slot);
    const float2 t = twF[p*16 + 2*r];
    const float cs = t.x;
    const float sn = (SGN > 0) ? t.y : -t.y;
    ldsA[(p*8 + r)*32 + ch] = cmul2(vA[slot], cs, sn);
    ldsB[(p*8 + r)*32 + ch] = cmul2(vB[slot], cs, sn);
  }
  __syncthreads();
  float4 tA[8], tB[8];
#pragma unroll
  for (int pp = 0; pp < 8; pp++){
    tA[pp] = ldsA[(pp*8 + p)*32 + ch];                 // s=2p
    tB[pp] = ldsB[(pp*8 + p)*32 + ch];
  }
  dft8v4<SGN>(tA);
  dft8v4<SGN>(tB);
#pragma unroll
  for (int t = 0; t < 8; t++){ vA[t] = tA[t]; vB[t] = tB[t]; }
  __syncthreads();
#pragma unroll
  for (int slot = 8; slot < 16; slot++){
    const int r = bitrev3(slot - 8);
    const float2 t = twF[p*16 + 2*r + 1];
    const float cs = t.x;
    const float sn = (SGN > 0) ? t.y : -t.y;
    ldsA[(p*8 + r)*32 + ch] = cmul2(vA[slot], cs, sn);
    ldsB[(p*8 + r)*32 + ch] = cmul2(vB[slot], cs, sn);
  }
  __syncthreads();
#pragma unroll
  for (int pp = 0; pp < 8; pp++){
    tA[pp] = ldsA[(pp*8 + p)*32 + ch];                 // s=2p+1
    tB[pp] = ldsB[(pp*8 + p)*32 + ch];
  }
  dft8v4<SGN>(tA);
  dft8v4<SGN>(tB);
#pragma unroll
  for (int t = 0; t < 8; t++){ vA[8 + t] = tA[t]; vB[8 + t] = tB[t]; }
}

// ---------------------------------------------------------------------------
// K1: forward step1 over n1 (64 nonzero of 128, zero-padded). 4 ch/thread,
// 16-B lanes on all global accesses. 128 channels/block.
// ---------------------------------------------------------------------------
__global__ __launch_bounds__(256, 2)
void k1_step1(const float* __restrict__ x, const float* __restrict__ h,
              unsigned* __restrict__ Az, unsigned* __restrict__ Ah){
  __shared__ float4 ldsA[64*32];
  __shared__ float4 ldsB[64*32];
  __shared__ float2 twF[128];
  __shared__ float2 twO[128];
  const int n2 = blockIdx.x, dg = blockIdx.y, mode = blockIdx.z;
  const int tid = threadIdx.x;
  const int ch = tid & 31, p = tid >> 5;
  const int d = dg*128 + 4*ch;                   // channels d..d+3

  build_twF(twF, tid);
  if (tid >= 128 && tid < 256){
    const int k1v = tid - 128;
    float sn, cs;
    __sincosf(-W_N * (float)(k1v * n2), &sn, &cs);   // e^{-i 2pi k1 n2 /16384}
    twO[k1v] = make_float2(cs, sn);
  }

  float4 vA[16], vB[16];
  if (mode == 0){
    const float* x0 = x;
    const float* x1 = x + (size_t)L_SEQ * D_CH;
#pragma unroll
    for (int q = 0; q < 8; q++){
      const size_t off = (size_t)(n2 + 128*(p + 8*q)) * D_CH + d;
      const float4 re = *(const float4*)(x0 + off);  // re of ch d..d+3
      const float4 im = *(const float4*)(x1 + off);  // im of ch d..d+3
      vA[q] = make_float4(re.x, im.x, re.y, im.y);
      vB[q] = make_float4(re.z, im.z, re.w, im.w);
    }
  } else {
#pragma unroll
    for (int q = 0; q < 8; q++){
      const size_t off = (size_t)(n2 + 128*(p + 8*q)) * D_CH + d;
      const float4 hv = *(const float4*)(h + off);
      vA[q] = make_float4(hv.x, 0.f, hv.y, 0.f);
      vB[q] = make_float4(hv.z, 0.f, hv.w, 0.f);
    }
  }
#pragma unroll
  for (int q = 8; q < 16; q++){
    vA[q] = make_float4(0.f, 0.f, 0.f, 0.f);
    vB[q] = make_float4(0.f, 0.f, 0.f, 0.f);
  }

  __syncthreads();                       // twiddle tables visible
  fft128v4x2<1>(vA, vB, ldsA, ldsB, twF, ch, p);

  unsigned* __restrict__ A = mode ? Ah : Az;
#pragma unroll
  for (int c = 0; c < 2; c++){
#pragma unroll
    for (int t = 0; t < 8; t++){
      const int k1v = (2*p + c) + 16*bitrev3(t);
      const float2 w = twO[k1v];
      const float4 rA = cmul2(vA[c*8 + t], w.x, w.y);
      const float4 rB = cmul2(vB[c*8 + t], w.x, w.y);
      *(uint4*)&A[((size_t)k1v*128 + n2)*D_CH + d] =
        make_uint4(packc(rA.x, rA.y), packc(rA.z, rA.w),
                   packc(rB.x, rB.y), packc(rB.z, rB.w));
    }
  }
}

// ---------------------------------------------------------------------------
// K2 (fused, 1 ch/thread, unchanged control): forward step2 for h
// (in-register Hspec) + forward step2 for z + pointwise Z*H/16384 +
// inverse DFT over k2, in place on A_z.
// ---------------------------------------------------------------------------
__global__ __launch_bounds__(256, 4)
void k2_zh(unsigned* __restrict__ Az, const unsigned* __restrict__ Ah){
  __shared__ float2 lds[64*NCH];
  __shared__ float2 twF[128];
  const int k1 = blockIdx.x, dg = blockIdx.y;
  const int tid = threadIdx.x;
  const int ch = tid & (NCH-1), p = tid >> 5;
  const int d = dg*NCH + ch;
  const size_t base = (size_t)k1 * 128 * D_CH + d;

  build_twF(twF, tid);

  unsigned ha[16], za[16];
#pragma unroll
  for (int q = 0; q < 16; q++)
    ha[q] = Ah[base + (size_t)(p + 8*q) * D_CH];
#pragma unroll
  for (int q = 0; q < 16; q++)
    za[q] = Az[base + (size_t)(p + 8*q) * D_CH];

  __syncthreads();                       // twF visible

  float2 v[16];
#pragma unroll
  for (int q = 0; q < 16; q++) v[q] = upk(ha[q]);
  fft128<1>(v, lds, twF, ch, p);
  unsigned hs[16];
  const float sc = 1.0f / 16384.0f;
#pragma unroll
  for (int i = 0; i < 16; i++) hs[i] = packc(v[i].x * sc, v[i].y * sc);
  __syncthreads();

#pragma unroll
  for (int q = 0; q < 16; q++) v[q] = upk(za[q]);
  fft128<1>(v, lds, twF, ch, p);

#pragma unroll
  for (int i = 0; i < 16; i++){
    const float2 hv = upk(hs[i]);
    const float zr = v[i].x, zi = v[i].y;
    v[i] = make_float2(zr*hv.x - zi*hv.y, zr*hv.y + zi*hv.x);
  }

  __syncthreads();
  float2 w[8];
#pragma unroll
  for (int c = 0; c < 2; c++)
#pragma unroll
    for (int t = 0; t < 8; t += 2){
      const int k2 = (2*p + c) + 16*bitrev3(t);
      lds[k2*NCH + ch] = v[c*8 + t];
    }
  __syncthreads();
#pragma unroll
  for (int q = 0; q < 8; q++) w[q] = lds[(p + 8*q)*NCH + ch];
  __syncthreads();
#pragma unroll
  for (int c = 0; c < 2; c++)
#pragma unroll
    for (int t = 1; t < 8; t += 2){
      const int k2 = (2*p + c) + 16*bitrev3(t) - 64;
      lds[k2*NCH + ch] = v[c*8 + t];
    }
  __syncthreads();
#pragma unroll
  for (int q = 0; q < 8; q++) v[8 + q] = lds[(p + 8*q)*NCH + ch];
  __syncthreads();
#pragma unroll
  for (int q = 0; q < 8; q++) v[q] = w[q];

  fft128<-1>(v, lds, twF, ch, p);

#pragma unroll
  for (int c = 0; c < 2; c++){
#pragma unroll
    for (int t = 0; t < 8; t++){
      const int m2 = (2*p + c) + 16*bitrev3(t);
      const float2 a = v[c*8 + t];
      Az[base + (size_t)m2 * D_CH] = packc(a.x, a.y);
    }
  }
}

// ---------------------------------------------------------------------------
// K3: inverse step2 over k1 + bias + output write. 4 ch/thread, 16-B lanes.
// y[0,t,d] = Re(w)+bias, y[1,t,d] = Im(w)+bias, t = m2 + 128*m1, m1 < 64.
// ---------------------------------------------------------------------------
__global__ __launch_bounds__(256, 2)
void k3_inv2(const unsigned* __restrict__ Bz, const float* __restrict__ bias,
             float* __restrict__ out){
  __shared__ float4 ldsA[64*32];
  __shared__ float4 ldsB[64*32];
  __shared__ float2 twF[128];
  __shared__ float2 twI[128];
  const int m2 = blockIdx.x, dg = blockIdx.y;
  const int tid = threadIdx.x;
  const int ch = tid & 31, p = tid >> 5;
  const int d = dg*128 + 4*ch;
  const float4 bv = *(const float4*)(bias + d);

  build_twF(twF, tid);
  if (tid >= 128 && tid < 256){
    const int k1 = tid - 128;
    float sn, cs;
    __sincosf(W_N * (float)(m2 * k1), &sn, &cs);     // e^{+i 2pi m2 k1 /16384}
    twI[k1] = make_float2(cs, sn);
  }

  uint4 raw[16];
#pragma unroll
  for (int q = 0; q < 16; q++){
    const int k1 = p + 8*q;
    raw[q] = *(const uint4*)&Bz[((size_t)k1*128 + m2) * D_CH + d];
  }

  __syncthreads();                       // tables visible

  float4 vA[16], vB[16];
#pragma unroll
  for (int q = 0; q < 16; q++){
    const float2 w = twI[p + 8*q];
    vA[q] = cmul2(upk2(raw[q].x, raw[q].y), w.x, w.y);
    vB[q] = cmul2(upk2(raw[q].z, raw[q].w), w.x, w.y);
  }

  fft128v4x2<-1>(vA, vB, ldsA, ldsB, twF, ch, p);

#pragma unroll
  for (int c = 0; c < 2; c++){
#pragma unroll
    for (int t = 0; t < 8; t += 2){      // t even <=> m1 < 64
      const int m1 = (2*p + c) + 16*bitrev3(t);
      const int tseq = m2 + 128*m1;
      const float4 a = vA[c*8 + t];
      const float4 b = vB[c*8 + t];
      *(float4*)&out[(size_t)tseq * D_CH + d] =
        make_float4(a.x + bv.x, a.z + bv.y, b.x + bv.z, b.z + bv.w);
      *(float4*)&out[(size_t)(L_SEQ + tseq) * D_CH + d] =
        make_float4(a.y + bv.x, a.w + bv.y, b.y + bv.z, b.w + bv.w);
    }
  }
}

// ---------------------------------------------------------------------------
extern "C" void kernel_launch(void* const* d_in, const int* in_sizes, int n_in,
                              void* d_out, int out_size, void* d_ws, size_t ws_size,
                              hipStream_t stream){
  (void)in_sizes; (void)n_in; (void)out_size;
  const float* x    = (const float*)d_in[0];
  const float* h    = (const float*)d_in[1];
  const float* bias = (const float*)d_in[2];
  float* out = (float*)d_out;

  const size_t REGION = (size_t)128 * 128 * D_CH * sizeof(unsigned); // 64 MiB
  unsigned *r1, *r2;
  if (ws_size >= 2 * REGION){
    r1 = (unsigned*)d_ws;                       // A_z -> b
    r2 = (unsigned*)((char*)d_ws + REGION);     // A_h
  } else {
    r1 = (unsigned*)d_out;  // safe: K3 reads each r1 cell before its stores
    r2 = (unsigned*)d_ws;   // requires ws_size >= 64 MiB
  }

  const dim3 blk(256, 1, 1);
  hipLaunchKernelGGL(k1_step1, dim3(128,8,2),  blk, 0, stream, x, h, r1, r2);
  hipLaunchKernelGGL(k2_zh,    dim3(128,32,1), blk, 0, stream, r1, r2);
  hipLaunchKernelGGL(k3_inv2,  dim3(128,8,1),  blk, 0, stream, r1, bias, out);
}